// Round 7
// baseline (1189.748 us; speedup 1.0000x reference)
//
#include <hip/hip_runtime.h>
#include <math.h>

#define Bsz 16
#define Tt 24
#define Nn 256
#define Fp 6
#define Hh 64
#define PredL 12
#define Fw 4
#define M1 32
#define TCHUNK 12
#define DEG2RAD 0.017453292519943295f
#define IDX2(t, b) ((t) * Bsz + (b))

// ---------------------------------------------------------------------------
// P0+PT: blocks 0..255 build packed pk[i][j] = {Ac,As}; block 256 repacks
// weights and zeroes the decoder barrier counter.
// ---------------------------------------------------------------------------
__global__ __launch_bounds__(256) void k_prep(
    const float* __restrict__ coords, const float* __restrict__ adj,
    const float* __restrict__ wgc2, const float* __restrict__ wih,
    const float* __restrict__ whh,  const float* __restrict__ wm1,
    const float* __restrict__ wm2,
    float2* __restrict__ pk,
    float* __restrict__ wgc2T, float* __restrict__ wm1T, float* __restrict__ wm2T,
    float4* __restrict__ wihP, float4* __restrict__ whhP,
    unsigned* __restrict__ ctr) {
  int tid = threadIdx.x;
  if (blockIdx.x < Nn) {
    int i = blockIdx.x;
    int j = tid;
    float dx = coords[2 * j]     - coords[2 * i];
    float dy = coords[2 * j + 1] - coords[2 * i + 1];
    float ang = atan2f(dy, dx);
    float a = adj[i * Nn + j];
    pk[i * Nn + j] = make_float2(a * cosf(ang), a * sinf(ang));
    return;
  }
  if (tid == 0) *ctr = 0u;
  for (int idx = tid; idx < Hh * Hh; idx += 256) {
    int g = idx / Hh, k = idx % Hh;
    wgc2T[k * Hh + g] = wgc2[g * Hh + k];
  }
  for (int idx = tid; idx < M1 * Hh; idx += 256) {
    int m = idx / Hh, k = idx % Hh;
    wm1T[k * M1 + m] = wm1[m * Hh + k];
  }
  for (int idx = tid; idx < Fp * M1; idx += 256) {
    int f = idx / M1, m = idx % M1;
    wm2T[m * Fp + f] = wm2[f * M1 + m];
  }
  for (int idx = tid; idx < Hh * 64; idx += 256) {
    int k = idx >> 6, lane = idx & 63;
    wihP[idx] = make_float4(wih[(0 * 64 + lane) * Hh + k],
                            wih[(1 * 64 + lane) * Hh + k],
                            wih[(2 * 64 + lane) * Hh + k], 0.f);
    whhP[idx] = make_float4(whh[(0 * 64 + lane) * Hh + k],
                            whh[(1 * 64 + lane) * Hh + k],
                            whh[(2 * 64 + lane) * Hh + k], 0.f);
  }
}

// ---------------------------------------------------------------------------
// E: fully fused encoder spatial block: deg + gconv1 + gconv2 + W2 -> sf_all.
// One block per (t,b), 128 threads, thread owns rows i and i+128.
// All adjacency reads are column reads pk[j*Nn + i] (coalesced), using
// val(i,j) = -val(j,i) off-diagonal.
// ---------------------------------------------------------------------------
__global__ __launch_bounds__(128, 1) void k_enc(
    const float2* __restrict__ pk, const float* __restrict__ hp,
    const float* __restrict__ hw,
    const float* __restrict__ wgc1, const float* __restrict__ bgc1,
    const float* __restrict__ wgc2T, const float* __restrict__ bgc2,
    float* __restrict__ sf_all,
    float* __restrict__ d23, float* __restrict__ e23) {
  __shared__ float d_lds[Nn];
  __shared__ float e_lds[Nn];
  __shared__ __align__(16) float u_s[Nn * 8];     // 8KB : u[j][f] = d_j x[j][f]
  __shared__ __align__(16) float h1_s[Nn * 68];   // 68KB: e_j-scaled h1 rows
  int tb = blockIdx.x, t = tb / Bsz, b = tb % Bsz;
  int tid = threadIdx.x;
  int ia = tid, ib = tid + 128;
  float spd = hw[(b * Tt + t) * Fw + 2];
  float rad = hw[(b * Tt + t) * Fw + 1] * DEG2RAD;
  float cr = cosf(rad), sr = sinf(rad);

  // ---- pass 0: degrees. F(j,i) = val(j,i); rs_i needs max(-F,0) off-diag,
  //      cs_i needs max(F,0). Both from column i. ----
  {
    float rs_a = 0.f, cs_a = 0.f, rs_b = 0.f, cs_b = 0.f;
#pragma unroll 4
    for (int j = 0; j < Nn; ++j) {
      float2 pa = pk[j * Nn + ia];
      float2 pb = pk[j * Nn + ib];
      float va = spd * (pa.x * cr + pa.y * sr);
      float vb = spd * (pb.x * cr + pb.y * sr);
      float vap = fmaxf(va, 0.f), vbp = fmaxf(vb, 0.f);
      cs_a += vap;
      cs_b += vbp;
      rs_a += (j == ia) ? vap : fmaxf(-va, 0.f);
      rs_b += (j == ib) ? vbp : fmaxf(-vb, 0.f);
    }
    d_lds[ia] = 1.f / (sqrtf(rs_a + 1.f) + 1e-6f);
    d_lds[ib] = 1.f / (sqrtf(rs_b + 1.f) + 1e-6f);
    e_lds[ia] = 1.f / (sqrtf(cs_a + 1.f) + 1e-6f);
    e_lds[ib] = 1.f / (sqrtf(cs_b + 1.f) + 1e-6f);
    if (t == Tt - 1) {
      d23[b * Nn + ia] = d_lds[ia]; d23[b * Nn + ib] = d_lds[ib];
      e23[b * Nn + ia] = e_lds[ia]; e23[b * Nn + ib] = e_lds[ib];
    }
  }
  __syncthreads();

  // ---- stage u = d_j * x ----
  {
    const float* xsrc = hp + (long)(b * Tt + t) * Nn * Fp;
    for (int idx = tid; idx < Nn * Fp; idx += 128) {
      int j = idx / Fp, f = idx - j * Fp;
      u_s[j * 8 + f] = d_lds[j] * xsrc[idx];
    }
    u_s[ia * 8 + 6] = 0.f; u_s[ia * 8 + 7] = 0.f;
    u_s[ib * 8 + 6] = 0.f; u_s[ib * 8 + 7] = 0.f;
  }
  __syncthreads();

  float da = d_lds[ia], db = d_lds[ib];
  float ea = e_lds[ia], eb = e_lds[ib];

  // ---- pass 1: gconv1 for 2 rows.  wout[i][j] = max(-F(j,i),0) off-diag ----
  float ya[Fp], yb[Fp];
  {
    float aa[Fp] = {0, 0, 0, 0, 0, 0}, ab[Fp] = {0, 0, 0, 0, 0, 0};
#pragma unroll 2
    for (int j = 0; j < Nn; ++j) {
      float2 pa = pk[j * Nn + ia];
      float2 pb = pk[j * Nn + ib];
      float va = spd * (pa.x * cr + pa.y * sr);
      float vb = spd * (pb.x * cr + pb.y * sr);
      float wa = (j == ia) ? fmaxf(va, 0.f) : fmaxf(-va, 0.f);
      float wb = (j == ib) ? fmaxf(vb, 0.f) : fmaxf(-vb, 0.f);
      float4 ul = *(const float4*)&u_s[j * 8];
      float4 uh = *(const float4*)&u_s[j * 8 + 4];
      aa[0] += wa * ul.x; aa[1] += wa * ul.y; aa[2] += wa * ul.z;
      aa[3] += wa * ul.w; aa[4] += wa * uh.x; aa[5] += wa * uh.y;
      ab[0] += wb * ul.x; ab[1] += wb * ul.y; ab[2] += wb * ul.z;
      ab[3] += wb * ul.w; ab[4] += wb * uh.x; ab[5] += wb * uh.y;
    }
#pragma unroll
    for (int f = 0; f < Fp; ++f) {
      ya[f] = da * (aa[f] + u_s[ia * 8 + f]);
      yb[f] = db * (ab[f] + u_s[ib * 8 + f]);
    }
  }

  // ---- h1 rows (e-scaled) into LDS ----
#pragma unroll
  for (int g4 = 0; g4 < 16; ++g4) {
    float4 hva, hvb;
#pragma unroll
    for (int q = 0; q < 4; ++q) {
      int g = g4 * 4 + q;
      float va = bgc1[g], vb = va;
#pragma unroll
      for (int f = 0; f < Fp; ++f) {
        float wg = wgc1[g * Fp + f];
        va += wg * ya[f];
        vb += wg * yb[f];
      }
      ((float*)&hva)[q] = fmaxf(va, 0.f) * ea;
      ((float*)&hvb)[q] = fmaxf(vb, 0.f) * eb;
    }
    *(float4*)&h1_s[ia * 68 + g4 * 4] = hva;
    *(float4*)&h1_s[ib * 68 + g4 * 4] = hvb;
  }
  __syncthreads();

  // ---- pass 2: z[i] = e_i * sum_j (win[i][j]+delta) * h1e[j]  (2 rows) ----
  float4 za[16], zb[16];
#pragma unroll
  for (int q = 0; q < 16; ++q) {
    za[q] = make_float4(0.f, 0.f, 0.f, 0.f);
    zb[q] = make_float4(0.f, 0.f, 0.f, 0.f);
  }
#pragma unroll 2
  for (int j = 0; j < Nn; ++j) {
    float2 pa = pk[j * Nn + ia];
    float2 pb = pk[j * Nn + ib];
    float va = spd * (pa.x * cr + pa.y * sr);
    float vb = spd * (pb.x * cr + pb.y * sr);
    float wfa = fmaxf(va, 0.f) + ((j == ia) ? 1.f : 0.f);
    float wfb = fmaxf(vb, 0.f) + ((j == ib) ? 1.f : 0.f);
#pragma unroll
    for (int g4 = 0; g4 < 16; ++g4) {
      float4 h4 = *(const float4*)&h1_s[j * 68 + g4 * 4];
      za[g4].x += wfa * h4.x; za[g4].y += wfa * h4.y;
      za[g4].z += wfa * h4.z; za[g4].w += wfa * h4.w;
      zb[g4].x += wfb * h4.x; zb[g4].y += wfb * h4.y;
      zb[g4].z += wfb * h4.z; zb[g4].w += wfb * h4.w;
    }
  }
#pragma unroll
  for (int q = 0; q < 16; ++q) {
    za[q].x *= ea; za[q].y *= ea; za[q].z *= ea; za[q].w *= ea;
    zb[q].x *= eb; zb[q].y *= eb; zb[q].z *= eb; zb[q].w *= eb;
  }

  // ---- W2 + relu -> sf_all (uniform wgc2T reads -> scalar path) ----
  long base = (long)IDX2(t, b) * Nn * Hh;
#pragma unroll
  for (int c = 0; c < 4; ++c) {
    float sa[16], sb[16];
#pragma unroll
    for (int q = 0; q < 16; ++q) { sa[q] = bgc2[c * 16 + q]; sb[q] = sa[q]; }
#pragma unroll
    for (int k4 = 0; k4 < 16; ++k4) {
#pragma unroll
      for (int e = 0; e < 4; ++e) {
        int k = k4 * 4 + e;
        float zka = ((const float*)&za[k4])[e];
        float zkb = ((const float*)&zb[k4])[e];
#pragma unroll
        for (int q = 0; q < 16; ++q) {
          float wk = wgc2T[k * Hh + c * 16 + q];
          sa[q] += wk * zka;
          sb[q] += wk * zkb;
        }
      }
    }
#pragma unroll
    for (int q4 = 0; q4 < 4; ++q4) {
      float4 va = make_float4(fmaxf(sa[q4 * 4 + 0], 0.f), fmaxf(sa[q4 * 4 + 1], 0.f),
                              fmaxf(sa[q4 * 4 + 2], 0.f), fmaxf(sa[q4 * 4 + 3], 0.f));
      float4 vb = make_float4(fmaxf(sb[q4 * 4 + 0], 0.f), fmaxf(sb[q4 * 4 + 1], 0.f),
                              fmaxf(sb[q4 * 4 + 2], 0.f), fmaxf(sb[q4 * 4 + 3], 0.f));
      *(float4*)&sf_all[base + (long)ia * Hh + c * 16 + q4 * 4] = va;
      *(float4*)&sf_all[base + (long)ib * Hh + c * 16 + q4 * 4] = vb;
    }
  }
}

// ---------------------------------------------------------------------------
// GI: gi = sf @ W_ih^T + b_ih for TCHUNK timesteps (16 rows/wave, VALU-bound)
// ---------------------------------------------------------------------------
__global__ __launch_bounds__(256) void k_gi(
    const float* __restrict__ sf_all, const float4* __restrict__ wihP,
    const float* __restrict__ bih, float* __restrict__ gi, int t0) {
  __shared__ float sf_c[4][16][64];
  int tid = threadIdx.x, w = tid >> 6, lane = tid & 63;
  int rowc0 = blockIdx.x * 64 + w * 16;
  long rowg0 = (long)t0 * (Bsz * Nn) + rowc0;
#pragma unroll
  for (int rr = 0; rr < 16; ++rr)
    sf_c[w][rr][lane] = sf_all[(rowg0 + rr) * Hh + lane];
  float bi_r = bih[lane], bi_z = bih[64 + lane], bi_n = bih[128 + lane];
  float ar[16], az[16], an[16];
#pragma unroll
  for (int rr = 0; rr < 16; ++rr) { ar[rr] = bi_r; az[rr] = bi_z; an[rr] = bi_n; }
#pragma unroll 2
  for (int kb = 0; kb < 16; ++kb) {
    int k0 = kb * 4;
    float4 wi0 = wihP[(k0 + 0) * 64 + lane];
    float4 wi1 = wihP[(k0 + 1) * 64 + lane];
    float4 wi2 = wihP[(k0 + 2) * 64 + lane];
    float4 wi3 = wihP[(k0 + 3) * 64 + lane];
#pragma unroll
    for (int rr = 0; rr < 16; ++rr) {
      const float4 s4 = *(const float4*)&sf_c[w][rr][k0];
      ar[rr] += s4.x * wi0.x + s4.y * wi1.x + s4.z * wi2.x + s4.w * wi3.x;
      az[rr] += s4.x * wi0.y + s4.y * wi1.y + s4.z * wi2.y + s4.w * wi3.y;
      an[rr] += s4.x * wi0.z + s4.y * wi1.z + s4.z * wi2.z + s4.w * wi3.z;
    }
  }
#pragma unroll
  for (int rr = 0; rr < 16; ++rr) {
    long rowc = rowc0 + rr;
    gi[(rowc * 3 + 0) * 64 + lane] = ar[rr];
    gi[(rowc * 3 + 1) * 64 + lane] = az[rr];
    gi[(rowc * 3 + 2) * 64 + lane] = an[rr];
  }
}

// ---------------------------------------------------------------------------
// GRU scan over one chunk (gh only; whh streamed; h broadcast via LDS rows)
// ---------------------------------------------------------------------------
__global__ __launch_bounds__(256) void k_gru_scan4(
    const float* __restrict__ gi, const float4* __restrict__ whhP,
    const float* __restrict__ bhh, float* __restrict__ hstate,
    int t0, int nt) {
  __shared__ float h_s[16][64];
  int b = blockIdx.x >> 4;
  int i0 = (blockIdx.x & 15) * 16;
  int tid = threadIdx.x, w = tid >> 6, lane = tid & 63;
  float bh_r = bhh[lane], bh_z = bhh[64 + lane], bh_n = bhh[128 + lane];
  float h_reg[4];
#pragma unroll
  for (int rr = 0; rr < 4; ++rr) {
    float hv = (t0 == 0) ? 0.f
                         : hstate[((long)b * Nn + i0 + w * 4 + rr) * Hh + lane];
    h_reg[rr] = hv;
    h_s[w * 4 + rr][lane] = hv;
  }
  for (int tl = 0; tl < nt; ++tl) {
    long rbase = ((long)tl * Bsz + b) * Nn + i0 + w * 4;
    float gr[4], gz[4], gn[4], hr[4], hz[4], hn[4];
#pragma unroll
    for (int rr = 0; rr < 4; ++rr) {
      gr[rr] = gi[((rbase + rr) * 3 + 0) * 64 + lane];
      gz[rr] = gi[((rbase + rr) * 3 + 1) * 64 + lane];
      gn[rr] = gi[((rbase + rr) * 3 + 2) * 64 + lane];
      hr[rr] = bh_r; hz[rr] = bh_z; hn[rr] = bh_n;
    }
#pragma unroll 4
    for (int kb = 0; kb < 16; ++kb) {
      int k0 = kb * 4;
      float4 wh0 = whhP[(k0 + 0) * 64 + lane];
      float4 wh1 = whhP[(k0 + 1) * 64 + lane];
      float4 wh2 = whhP[(k0 + 2) * 64 + lane];
      float4 wh3 = whhP[(k0 + 3) * 64 + lane];
#pragma unroll
      for (int rr = 0; rr < 4; ++rr) {
        const float4 h4 = *(const float4*)&h_s[w * 4 + rr][k0];
        hr[rr] += h4.x * wh0.x + h4.y * wh1.x + h4.z * wh2.x + h4.w * wh3.x;
        hz[rr] += h4.x * wh0.y + h4.y * wh1.y + h4.z * wh2.y + h4.w * wh3.y;
        hn[rr] += h4.x * wh0.z + h4.y * wh1.z + h4.z * wh2.z + h4.w * wh3.z;
      }
    }
#pragma unroll
    for (int rr = 0; rr < 4; ++rr) {
      float rg = 1.f / (1.f + expf(-(gr[rr] + hr[rr])));
      float zg = 1.f / (1.f + expf(-(gz[rr] + hz[rr])));
      float ng = tanhf(gn[rr] + rg * hn[rr]);
      float hv = (1.f - zg) * ng + zg * h_reg[rr];
      h_reg[rr] = hv;
      h_s[w * 4 + rr][lane] = hv;
    }
  }
#pragma unroll
  for (int rr = 0; rr < 4; ++rr)
    hstate[((long)b * Nn + i0 + w * 4 + rr) * Hh + lane] = h_reg[rr];
}

// ---------------------------------------------------------------------------
// D0: decoder normalized adjacencies: A1d[i][j], A2d[i][j] (t = Tt-1)
// ---------------------------------------------------------------------------
__global__ __launch_bounds__(256) void k_norm_dec(
    const float* __restrict__ hw, const float2* __restrict__ pk,
    const float* __restrict__ d23, const float* __restrict__ e23,
    float* __restrict__ A1d, float* __restrict__ A2d) {
  int b = blockIdx.x >> 8;
  int i = blockIdx.x & 255;
  int j = threadIdx.x;
  float spd = hw[(b * Tt + (Tt - 1)) * Fw + 2];
  float rad = hw[(b * Tt + (Tt - 1)) * Fw + 1] * DEG2RAD;
  float cr = cosf(rad), sr = sinf(rad);
  const float* drow = d23 + b * Nn;
  const float* erow = e23 + b * Nn;
  float2 pv = pk[i * Nn + j];
  float val = spd * (pv.x * cr + pv.y * sr);
  float dlt = (j == i) ? 1.f : 0.f;
  float wout = fmaxf(val, 0.f);
  float win  = (j == i) ? wout : fmaxf(-val, 0.f);
  A1d[((long)b * Nn + i) * Nn + j] = drow[i] * (wout + dlt) * drow[j];
  A2d[((long)b * Nn + i) * Nn + j] = erow[i] * (win + dlt) * erow[j];
}

// ---------------------------------------------------------------------------
// Persistent decoder: 256 blocks (1/CU), manual device-scope grid barriers.
// Block owns (b, rows i0..i0+15); h kept in registers across all 12 steps;
// A2 rows (wvT) staged in LDS once.
// ---------------------------------------------------------------------------
__device__ __forceinline__ void gridbar(unsigned* ctr, unsigned* tgt) {
  __syncthreads();
  *tgt += 256u;
  if (threadIdx.x == 0) {
    __threadfence();
    __hip_atomic_fetch_add(ctr, 1u, __ATOMIC_RELEASE, __HIP_MEMORY_SCOPE_AGENT);
    while (__hip_atomic_load(ctr, __ATOMIC_ACQUIRE, __HIP_MEMORY_SCOPE_AGENT) < *tgt)
      __builtin_amdgcn_s_sleep(2);
  }
  __syncthreads();
}

__global__ __launch_bounds__(256) void k_decoder(
    const float* __restrict__ A1d, const float* __restrict__ A2d,
    float* __restrict__ h1d, float* __restrict__ xb0, float* __restrict__ xb1,
    const float* __restrict__ hstate,
    const float4* __restrict__ wihP, const float4* __restrict__ whhP,
    const float* __restrict__ wgc2T, const float* __restrict__ wgc1,
    const float* __restrict__ bgc1, const float* __restrict__ bgc2,
    const float* __restrict__ bih, const float* __restrict__ bhh,
    const float* __restrict__ wm1T, const float* __restrict__ bm1,
    const float* __restrict__ wm2T, const float* __restrict__ bm2,
    float* __restrict__ outp, unsigned* __restrict__ ctr) {
  __shared__ __align__(16) float wvT[Nn * 20];   // 20KB: A2 rows, staged once
  __shared__ float x_lds[Nn * Fp];               // 6KB
  __shared__ float red[4][16][Hh];               // 16KB
  __shared__ float y2[16][Hh];
  __shared__ float sf_s[16][Hh];
  __shared__ float h_s[16][Hh];
  __shared__ float hn_lds[16][Hh];
  __shared__ float u_lds[16][M1];

  int b = blockIdx.x >> 4;
  int i0 = (blockIdx.x & 15) * 16;
  int tid = threadIdx.x, w = tid >> 6, lane = tid & 63;
  unsigned tgt = 0u;

#pragma unroll
  for (int r = 0; r < 16; ++r)
    wvT[tid * 20 + r] = A2d[((long)b * Nn + i0 + r) * Nn + tid];
  float hp_reg[4];
#pragma unroll
  for (int rr = 0; rr < 4; ++rr) {
    hp_reg[rr] = hstate[((long)b * Nn + i0 + w * 4 + rr) * Hh + lane];
    h_s[w * 4 + rr][lane] = hp_reg[rr];
    hn_lds[w * 4 + rr][lane] = hp_reg[rr];
  }
  float bi_r = bih[lane], bi_z = bih[64 + lane], bi_n = bih[128 + lane];
  float bh_r = bhh[lane], bh_z = bhh[64 + lane], bh_n = bhh[128 + lane];
  __syncthreads();

  // ---- dec0: x0 = mlp(h) for own rows -> xb0 ----
#pragma unroll
  for (int rep = 0; rep < 2; ++rep) {
    int idx = tid + rep * 256;
    int row = idx >> 5, m = idx & 31;
    float um = bm1[m];
    for (int k = 0; k < Hh; ++k) um += wm1T[k * M1 + m] * hn_lds[row][k];
    u_lds[row][m] = fmaxf(um, 0.f);
  }
  __syncthreads();
  if (tid < 16 * Fp) {
    int row = tid / Fp, f = tid % Fp;
    float pf = bm2[f];
#pragma unroll
    for (int m = 0; m < M1; ++m) pf += wm2T[m * Fp + f] * u_lds[row][m];
    xb0[((long)b * Nn + i0 + row) * Fp + f] = pf;
  }
  gridbar(ctr, &tgt);

  for (int p = 0; p < PredL; ++p) {
    const float* xin = (p & 1) ? xb1 : xb0;
    float* xout      = (p & 1) ? xb0 : xb1;

    // ---- phase A: gconv1 for own 16 rows -> h1d (global) ----
    for (int idx = tid; idx < Nn * Fp; idx += 256)
      x_lds[idx] = xin[(long)b * Nn * Fp + idx];
    __syncthreads();
#pragma unroll
    for (int rr = 0; rr < 4; ++rr) {
      int i = i0 + w * 4 + rr;
      const float* arow = A1d + ((long)b * Nn + i) * Nn;
      float acc[Fp] = {0.f, 0.f, 0.f, 0.f, 0.f, 0.f};
#pragma unroll
      for (int c = 0; c < 4; ++c) {
        int j = lane + 64 * c;
        float wt = arow[j];
#pragma unroll
        for (int f = 0; f < Fp; ++f) acc[f] += wt * x_lds[j * Fp + f];
      }
#pragma unroll
      for (int f = 0; f < Fp; ++f) {
#pragma unroll
        for (int off = 32; off; off >>= 1) acc[f] += __shfl_xor(acc[f], off);
      }
      float hv = bgc1[lane];
#pragma unroll
      for (int f = 0; f < Fp; ++f) hv += wgc1[lane * Fp + f] * acc[f];
      h1d[((long)b * Nn + i) * Hh + lane] = fmaxf(hv, 0.f);
    }
    gridbar(ctr, &tgt);

    // ---- phase B: agg + W2 + GRU + MLP ----
    float acc[16];
#pragma unroll
    for (int r = 0; r < 16; ++r) acc[r] = 0.f;
    const float* h1b = h1d + (long)b * Nn * Hh;
#pragma unroll 4
    for (int jj = 0; jj < 64; ++jj) {
      int j = w * 64 + jj;
      float hv = h1b[j * Hh + lane];
      const float4* wp = (const float4*)(wvT + j * 20);
      float4 w0 = wp[0], w1 = wp[1], w2 = wp[2], w3 = wp[3];
      acc[0] += w0.x * hv; acc[1] += w0.y * hv; acc[2] += w0.z * hv; acc[3] += w0.w * hv;
      acc[4] += w1.x * hv; acc[5] += w1.y * hv; acc[6] += w1.z * hv; acc[7] += w1.w * hv;
      acc[8] += w2.x * hv; acc[9] += w2.y * hv; acc[10] += w2.z * hv; acc[11] += w2.w * hv;
      acc[12] += w3.x * hv; acc[13] += w3.y * hv; acc[14] += w3.z * hv; acc[15] += w3.w * hv;
    }
#pragma unroll
    for (int r = 0; r < 16; ++r) red[w][r][lane] = acc[r];
    __syncthreads();
#pragma unroll
    for (int rr = 0; rr < 4; ++rr) {
      int r = w * 4 + rr;
      y2[r][lane] = red[0][r][lane] + red[1][r][lane] + red[2][r][lane] + red[3][r][lane];
    }
    {
      float a0 = bgc2[lane], a1 = a0, a2 = a0, a3 = a0;
      for (int k = 0; k < Hh; ++k) {
        float wk = wgc2T[k * Hh + lane];
        a0 += wk * y2[w * 4 + 0][k];
        a1 += wk * y2[w * 4 + 1][k];
        a2 += wk * y2[w * 4 + 2][k];
        a3 += wk * y2[w * 4 + 3][k];
      }
      sf_s[w * 4 + 0][lane] = fmaxf(a0, 0.f);
      sf_s[w * 4 + 1][lane] = fmaxf(a1, 0.f);
      sf_s[w * 4 + 2][lane] = fmaxf(a2, 0.f);
      sf_s[w * 4 + 3][lane] = fmaxf(a3, 0.f);
    }
    // GRU (weights streamed from global/L2)
    {
      float gir[4], giz[4], gin[4], ghr[4], ghz[4], ghn[4];
#pragma unroll
      for (int rr = 0; rr < 4; ++rr) {
        gir[rr] = bi_r; giz[rr] = bi_z; gin[rr] = bi_n;
        ghr[rr] = bh_r; ghz[rr] = bh_z; ghn[rr] = bh_n;
      }
#pragma unroll 4
      for (int kb = 0; kb < 16; ++kb) {
        int k0 = kb * 4;
        float4 wi[4], wh[4];
#pragma unroll
        for (int q = 0; q < 4; ++q) {
          wi[q] = wihP[(k0 + q) * 64 + lane];
          wh[q] = whhP[(k0 + q) * 64 + lane];
        }
#pragma unroll
        for (int rr = 0; rr < 4; ++rr) {
          const float4 s4 = *(const float4*)&sf_s[w * 4 + rr][k0];
          const float4 h4 = *(const float4*)&h_s[w * 4 + rr][k0];
          gir[rr] += s4.x * wi[0].x + s4.y * wi[1].x + s4.z * wi[2].x + s4.w * wi[3].x;
          giz[rr] += s4.x * wi[0].y + s4.y * wi[1].y + s4.z * wi[2].y + s4.w * wi[3].y;
          gin[rr] += s4.x * wi[0].z + s4.y * wi[1].z + s4.z * wi[2].z + s4.w * wi[3].z;
          ghr[rr] += h4.x * wh[0].x + h4.y * wh[1].x + h4.z * wh[2].x + h4.w * wh[3].x;
          ghz[rr] += h4.x * wh[0].y + h4.y * wh[1].y + h4.z * wh[2].y + h4.w * wh[3].y;
          ghn[rr] += h4.x * wh[0].z + h4.y * wh[1].z + h4.z * wh[2].z + h4.w * wh[3].z;
        }
      }
#pragma unroll
      for (int rr = 0; rr < 4; ++rr) {
        float rg = 1.f / (1.f + expf(-(gir[rr] + ghr[rr])));
        float zg = 1.f / (1.f + expf(-(giz[rr] + ghz[rr])));
        float ng = tanhf(gin[rr] + rg * ghn[rr]);
        float hn = (1.f - zg) * ng + zg * hp_reg[rr];
        hp_reg[rr] = hn;
      }
    }
    __syncthreads();  // all waves done with h_s / sf_s before overwrite
#pragma unroll
    for (int rr = 0; rr < 4; ++rr) {
      h_s[w * 4 + rr][lane] = hp_reg[rr];
      hn_lds[w * 4 + rr][lane] = hp_reg[rr];
    }
    __syncthreads();
    // MLP -> out, xout
#pragma unroll
    for (int rep = 0; rep < 2; ++rep) {
      int idx = tid + rep * 256;
      int row = idx >> 5, m = idx & 31;
      float um = bm1[m];
      for (int k = 0; k < Hh; ++k) um += wm1T[k * M1 + m] * hn_lds[row][k];
      u_lds[row][m] = fmaxf(um, 0.f);
    }
    __syncthreads();
    if (tid < 16 * Fp) {
      int row = tid / Fp, f = tid % Fp;
      float pf = bm2[f];
#pragma unroll
      for (int m = 0; m < M1; ++m) pf += wm2T[m * Fp + f] * u_lds[row][m];
      int i = i0 + row;
      outp[(((long)b * PredL + p) * Nn + i) * Fp + f] = pf;
      xout[((long)b * Nn + i) * Fp + f] = pf;
    }
    gridbar(ctr, &tgt);
  }
}

// ---------------------------------------------------------------------------
extern "C" void kernel_launch(void* const* d_in, const int* in_sizes, int n_in,
                              void* d_out, int out_size, void* d_ws, size_t ws_size,
                              hipStream_t stream) {
  const float* hp     = (const float*)d_in[0];
  const float* hw     = (const float*)d_in[1];
  const float* adj    = (const float*)d_in[2];
  const float* coords = (const float*)d_in[3];
  const float* wgc1   = (const float*)d_in[4];
  const float* bgc1   = (const float*)d_in[5];
  const float* wgc2   = (const float*)d_in[6];
  const float* bgc2   = (const float*)d_in[7];
  const float* wih    = (const float*)d_in[8];
  const float* whh    = (const float*)d_in[9];
  const float* bih    = (const float*)d_in[10];
  const float* bhh    = (const float*)d_in[11];
  const float* wm1    = (const float*)d_in[12];
  const float* bm1    = (const float*)d_in[13];
  const float* wm2    = (const float*)d_in[14];
  const float* bm2    = (const float*)d_in[15];
  float* out = (float*)d_out;

  float* w = (float*)d_ws;
  float2* pk    = (float2*)w; w += Nn * Nn * 2;
  float* d23    = w; w += Bsz * Nn;
  float* e23    = w; w += Bsz * Nn;
  float* hstate = w; w += Bsz * Nn * Hh;
  float* sf_all = w; w += (long)Tt * Bsz * Nn * Hh;
  float* gi_ch  = w; w += (long)TCHUNK * Bsz * Nn * 3 * 64;
  float* h1d    = w; w += Bsz * Nn * Hh;
  float* xb0    = w; w += Bsz * Nn * Fp;
  float* xb1    = w; w += Bsz * Nn * Fp;
  float* A1d    = w; w += Bsz * Nn * Nn;
  float* A2d    = w; w += Bsz * Nn * Nn;
  float* wgc2T  = w; w += Hh * Hh;
  float* wm1T   = w; w += Hh * M1;
  float* wm2T   = w; w += M1 * Fp;
  float4* wihP  = (float4*)w; w += Hh * 64 * 4;
  float4* whhP  = (float4*)w; w += Hh * 64 * 4;
  unsigned* ctr = (unsigned*)w; w += 4;

  k_prep<<<Nn + 1, 256, 0, stream>>>(coords, adj, wgc2, wih, whh, wm1, wm2,
                                     pk, wgc2T, wm1T, wm2T, wihP, whhP, ctr);
  k_enc<<<Tt * Bsz, 128, 0, stream>>>(pk, hp, hw, wgc1, bgc1, wgc2T, bgc2,
                                      sf_all, d23, e23);
  for (int s = 0; s < Tt / TCHUNK; ++s) {
    int t0 = s * TCHUNK;
    k_gi<<<(TCHUNK * Bsz * Nn) / 64, 256, 0, stream>>>(sf_all, wihP, bih,
                                                       gi_ch, t0);
    k_gru_scan4<<<Bsz * 16, 256, 0, stream>>>(gi_ch, whhP, bhh, hstate,
                                              t0, TCHUNK);
  }
  k_norm_dec<<<Bsz * Nn, 256, 0, stream>>>(hw, pk, d23, e23, A1d, A2d);

  k_decoder<<<Bsz * 16, 256, 0, stream>>>(
      A1d, A2d, h1d, xb0, xb1, hstate, wihP, whhP, wgc2T, wgc1, bgc1, bgc2,
      bih, bhh, wm1T, bm1, wm2T, bm2, out, ctr);
}

// Round 8
// 762.617 us; speedup vs baseline: 1.5601x; 1.5601x over previous
//
#include <hip/hip_runtime.h>
#include <math.h>

#define Bsz 16
#define Tt 24
#define Nn 256
#define Fp 6
#define Hh 64
#define PredL 12
#define Fw 4
#define M1 32
#define TCHUNK 12
#define DEG2RAD 0.017453292519943295f
#define IDX2(t, b) ((t) * Bsz + (b))

// ---------------------------------------------------------------------------
// P0+PT: blocks 0..255 build packed pk[i][j] = {Ac,As}; block 256 repacks
// weights (wgc2T[k][g], wm1T, wm2T, wihP/whhP float4 {r,z,n,0} per [k][lane]).
// ---------------------------------------------------------------------------
__global__ __launch_bounds__(256) void k_prep(
    const float* __restrict__ coords, const float* __restrict__ adj,
    const float* __restrict__ wgc2, const float* __restrict__ wih,
    const float* __restrict__ whh,  const float* __restrict__ wm1,
    const float* __restrict__ wm2,
    float2* __restrict__ pk,
    float* __restrict__ wgc2T, float* __restrict__ wm1T, float* __restrict__ wm2T,
    float4* __restrict__ wihP, float4* __restrict__ whhP) {
  int tid = threadIdx.x;
  if (blockIdx.x < Nn) {
    int i = blockIdx.x;
    int j = tid;
    float dx = coords[2 * j]     - coords[2 * i];
    float dy = coords[2 * j + 1] - coords[2 * i + 1];
    float ang = atan2f(dy, dx);
    float a = adj[i * Nn + j];
    pk[i * Nn + j] = make_float2(a * cosf(ang), a * sinf(ang));
    return;
  }
  for (int idx = tid; idx < Hh * Hh; idx += 256) {
    int g = idx / Hh, k = idx % Hh;
    wgc2T[k * Hh + g] = wgc2[g * Hh + k];
  }
  for (int idx = tid; idx < M1 * Hh; idx += 256) {
    int m = idx / Hh, k = idx % Hh;
    wm1T[k * M1 + m] = wm1[m * Hh + k];
  }
  for (int idx = tid; idx < Fp * M1; idx += 256) {
    int f = idx / M1, m = idx % M1;
    wm2T[m * Fp + f] = wm2[f * M1 + m];
  }
  for (int idx = tid; idx < Hh * 64; idx += 256) {
    int k = idx >> 6, lane = idx & 63;
    wihP[idx] = make_float4(wih[(0 * 64 + lane) * Hh + k],
                            wih[(1 * 64 + lane) * Hh + k],
                            wih[(2 * 64 + lane) * Hh + k], 0.f);
    whhP[idx] = make_float4(whh[(0 * 64 + lane) * Hh + k],
                            whh[(1 * 64 + lane) * Hh + k],
                            whh[(2 * 64 + lane) * Hh + k], 0.f);
  }
}

// ---------------------------------------------------------------------------
// E: fused encoder spatial block: deg + gconv1 + gconv2 + W2 -> sf_all.
// One block per (t,b), 256 threads, 2 blocks/CU (79.9KB LDS).
// V(j,i) read from pk[j*Nn+i] (coalesced); val(i,j) = -V(j,i) off-diagonal.
// Pass-2 uses 8x8 register tiling: thread (rb,gb) owns rows rb*8..+7 and
// g's gb*8..+7 -> 2 LDS b128 + 8 global float2 per j feed 64 FMA.
// ---------------------------------------------------------------------------
__global__ __launch_bounds__(256, 2) void k_enc(
    const float2* __restrict__ pk, const float* __restrict__ hp,
    const float* __restrict__ hw,
    const float* __restrict__ wgc1, const float* __restrict__ bgc1,
    const float* __restrict__ wgc2T, const float* __restrict__ bgc2,
    float* __restrict__ sf_all,
    float* __restrict__ d23, float* __restrict__ e23) {
  __shared__ float d_lds[Nn];
  __shared__ float e_lds[Nn];
  __shared__ __align__(16) float u_s[Nn * 8];     // 8KB : u[j][f] = d_j x[j][f]
  __shared__ __align__(16) float h1_s[Nn * 68];   // 69.6KB: [j][68]
  int tb = blockIdx.x, t = tb / Bsz, b = tb % Bsz;
  int tid = threadIdx.x;
  float spd = hw[(b * Tt + t) * Fw + 2];
  float rad = hw[(b * Tt + t) * Fw + 1] * DEG2RAD;
  float scr = spd * cosf(rad), ssr = spd * sinf(rad);

  // ---- pass 0: degrees for row i = tid (all from column i of pk) ----
  {
    int i = tid;
    float rs = 0.f, cs = 0.f;
#pragma unroll 4
    for (int j = 0; j < Nn; ++j) {
      float2 pv = pk[j * Nn + i];
      float v = pv.x * scr + pv.y * ssr;   // V(j,i)
      cs += fmaxf(v, 0.f);
      rs += fmaxf(-v, 0.f);
    }
    float2 pd = pk[i * Nn + i];
    float vii = pd.x * scr + pd.y * ssr;
    rs += vii;  // diag fix: max(vii,0) - max(-vii,0) = vii
    float di = 1.f / (sqrtf(rs + 1.f) + 1e-6f);
    float ei = 1.f / (sqrtf(cs + 1.f) + 1e-6f);
    d_lds[i] = di; e_lds[i] = ei;
    if (t == Tt - 1) { d23[b * Nn + i] = di; e23[b * Nn + i] = ei; }
  }
  __syncthreads();

  // ---- stage u = d_j * x ----
  {
    const float* xsrc = hp + (long)(b * Tt + t) * Nn * Fp;
    for (int idx = tid; idx < Nn * Fp; idx += 256) {
      int j = idx / Fp, f = idx - j * Fp;
      u_s[j * 8 + f] = d_lds[j] * xsrc[idx];
    }
    u_s[tid * 8 + 6] = 0.f;
    u_s[tid * 8 + 7] = 0.f;
  }
  __syncthreads();

  // ---- pass 1: gconv1 for row i = tid; h1e row -> LDS ----
  {
    int i = tid;
    float a0 = 0.f, a1 = 0.f, a2 = 0.f, a3 = 0.f, a4 = 0.f, a5 = 0.f;
#pragma unroll 2
    for (int j = 0; j < Nn; ++j) {
      float2 pv = pk[j * Nn + i];
      float v = pv.x * scr + pv.y * ssr;      // V(j,i)
      float w = fmaxf(-v, 0.f);               // wout[i][j], wrong on diag
      float4 ul = *(const float4*)&u_s[j * 8];
      float4 uh = *(const float4*)&u_s[j * 8 + 4];
      a0 += w * ul.x; a1 += w * ul.y; a2 += w * ul.z;
      a3 += w * ul.w; a4 += w * uh.x; a5 += w * uh.y;
    }
    float2 pd = pk[i * Nn + i];
    float vii = pd.x * scr + pd.y * ssr;
    float di = d_lds[i], ei = e_lds[i];
    // diag fix (+vii*u_i) and +I term (+u_i): acc + (vii+1)*u_i
    float c1 = vii + 1.f;
    float y0 = di * (a0 + c1 * u_s[i * 8 + 0]);
    float y1 = di * (a1 + c1 * u_s[i * 8 + 1]);
    float y2 = di * (a2 + c1 * u_s[i * 8 + 2]);
    float y3 = di * (a3 + c1 * u_s[i * 8 + 3]);
    float y4 = di * (a4 + c1 * u_s[i * 8 + 4]);
    float y5 = di * (a5 + c1 * u_s[i * 8 + 5]);
#pragma unroll
    for (int g4 = 0; g4 < 16; ++g4) {
      float4 hv;
#pragma unroll
      for (int q = 0; q < 4; ++q) {
        int g = g4 * 4 + q;
        float v2 = bgc1[g] + wgc1[g * Fp + 0] * y0 + wgc1[g * Fp + 1] * y1 +
                   wgc1[g * Fp + 2] * y2 + wgc1[g * Fp + 3] * y3 +
                   wgc1[g * Fp + 4] * y4 + wgc1[g * Fp + 5] * y5;
        ((float*)&hv)[q] = fmaxf(v2, 0.f) * ei;
      }
      *(float4*)&h1_s[i * 68 + g4 * 4] = hv;
    }
  }
  __syncthreads();

  // ---- pass 2: 8x8 tiled z = (Win + I) * h1e ----
  int gb = tid >> 5, rb = tid & 31;
  int i0r = rb * 8, g0 = gb * 8;
  float z[8][8];
#pragma unroll
  for (int r = 0; r < 8; ++r)
#pragma unroll
    for (int q = 0; q < 8; ++q) z[r][q] = 0.f;
#pragma unroll 2
  for (int j = 0; j < Nn; ++j) {
    float4 hA = *(const float4*)&h1_s[j * 68 + g0];
    float4 hB = *(const float4*)&h1_s[j * 68 + g0 + 4];
    const float4* pkr = (const float4*)(pk + (long)j * Nn + i0r);
    float4 p0 = pkr[0], p1 = pkr[1], p2 = pkr[2], p3 = pkr[3];
    float wv[8];
    wv[0] = fmaxf(p0.x * scr + p0.y * ssr, 0.f);   // win[i0r+0][j] = max(V(j,i),0)
    wv[1] = fmaxf(p0.z * scr + p0.w * ssr, 0.f);
    wv[2] = fmaxf(p1.x * scr + p1.y * ssr, 0.f);
    wv[3] = fmaxf(p1.z * scr + p1.w * ssr, 0.f);
    wv[4] = fmaxf(p2.x * scr + p2.y * ssr, 0.f);
    wv[5] = fmaxf(p2.z * scr + p2.w * ssr, 0.f);
    wv[6] = fmaxf(p3.x * scr + p3.y * ssr, 0.f);
    wv[7] = fmaxf(p3.z * scr + p3.w * ssr, 0.f);
#pragma unroll
    for (int r = 0; r < 8; ++r) {
      z[r][0] += wv[r] * hA.x; z[r][1] += wv[r] * hA.y;
      z[r][2] += wv[r] * hA.z; z[r][3] += wv[r] * hA.w;
      z[r][4] += wv[r] * hB.x; z[r][5] += wv[r] * hB.y;
      z[r][6] += wv[r] * hB.z; z[r][7] += wv[r] * hB.w;
    }
  }
  // + identity term, * e_i
#pragma unroll
  for (int r = 0; r < 8; ++r) {
    int i = i0r + r;
    float4 hA = *(const float4*)&h1_s[i * 68 + g0];
    float4 hB = *(const float4*)&h1_s[i * 68 + g0 + 4];
    float ei = e_lds[i];
    z[r][0] = (z[r][0] + hA.x) * ei; z[r][1] = (z[r][1] + hA.y) * ei;
    z[r][2] = (z[r][2] + hA.z) * ei; z[r][3] = (z[r][3] + hA.w) * ei;
    z[r][4] = (z[r][4] + hB.x) * ei; z[r][5] = (z[r][5] + hB.y) * ei;
    z[r][6] = (z[r][6] + hB.z) * ei; z[r][7] = (z[r][7] + hB.w) * ei;
  }
  __syncthreads();   // all pass-2 reads of h1_s done
#pragma unroll
  for (int r = 0; r < 8; ++r) {
    *(float4*)&h1_s[(i0r + r) * 68 + g0] =
        make_float4(z[r][0], z[r][1], z[r][2], z[r][3]);
    *(float4*)&h1_s[(i0r + r) * 68 + g0 + 4] =
        make_float4(z[r][4], z[r][5], z[r][6], z[r][7]);
  }
  __syncthreads();

  // ---- W2 + relu -> sf_all (thread = row; wgc2T reads uniform/scalar) ----
  {
    int i = tid;
    float4 zr[16];
#pragma unroll
    for (int k4 = 0; k4 < 16; ++k4)
      zr[k4] = *(const float4*)&h1_s[i * 68 + k4 * 4];
    long base = (long)IDX2(t, b) * Nn * Hh + (long)i * Hh;
#pragma unroll
    for (int c = 0; c < 4; ++c) {
      float s[16];
#pragma unroll
      for (int q = 0; q < 16; ++q) s[q] = bgc2[c * 16 + q];
#pragma unroll
      for (int k4 = 0; k4 < 16; ++k4) {
#pragma unroll
        for (int e = 0; e < 4; ++e) {
          int k = k4 * 4 + e;
          float zk = ((const float*)&zr[k4])[e];
#pragma unroll
          for (int q = 0; q < 16; ++q)
            s[q] += wgc2T[k * Hh + c * 16 + q] * zk;
        }
      }
#pragma unroll
      for (int q4 = 0; q4 < 4; ++q4) {
        float4 sv = make_float4(fmaxf(s[q4 * 4 + 0], 0.f), fmaxf(s[q4 * 4 + 1], 0.f),
                                fmaxf(s[q4 * 4 + 2], 0.f), fmaxf(s[q4 * 4 + 3], 0.f));
        *(float4*)&sf_all[base + c * 16 + q4 * 4] = sv;
      }
    }
  }
}

// ---------------------------------------------------------------------------
// GI: gi = sf @ W_ih^T + b_ih for TCHUNK timesteps (16 rows/wave, VALU-bound)
// ---------------------------------------------------------------------------
__global__ __launch_bounds__(256) void k_gi(
    const float* __restrict__ sf_all, const float4* __restrict__ wihP,
    const float* __restrict__ bih, float* __restrict__ gi, int t0) {
  __shared__ float sf_c[4][16][64];
  int tid = threadIdx.x, w = tid >> 6, lane = tid & 63;
  int rowc0 = blockIdx.x * 64 + w * 16;
  long rowg0 = (long)t0 * (Bsz * Nn) + rowc0;
#pragma unroll
  for (int rr = 0; rr < 16; ++rr)
    sf_c[w][rr][lane] = sf_all[(rowg0 + rr) * Hh + lane];
  float bi_r = bih[lane], bi_z = bih[64 + lane], bi_n = bih[128 + lane];
  float ar[16], az[16], an[16];
#pragma unroll
  for (int rr = 0; rr < 16; ++rr) { ar[rr] = bi_r; az[rr] = bi_z; an[rr] = bi_n; }
#pragma unroll 2
  for (int kb = 0; kb < 16; ++kb) {
    int k0 = kb * 4;
    float4 wi0 = wihP[(k0 + 0) * 64 + lane];
    float4 wi1 = wihP[(k0 + 1) * 64 + lane];
    float4 wi2 = wihP[(k0 + 2) * 64 + lane];
    float4 wi3 = wihP[(k0 + 3) * 64 + lane];
#pragma unroll
    for (int rr = 0; rr < 16; ++rr) {
      const float4 s4 = *(const float4*)&sf_c[w][rr][k0];
      ar[rr] += s4.x * wi0.x + s4.y * wi1.x + s4.z * wi2.x + s4.w * wi3.x;
      az[rr] += s4.x * wi0.y + s4.y * wi1.y + s4.z * wi2.y + s4.w * wi3.y;
      an[rr] += s4.x * wi0.z + s4.y * wi1.z + s4.z * wi2.z + s4.w * wi3.z;
    }
  }
#pragma unroll
  for (int rr = 0; rr < 16; ++rr) {
    long rowc = rowc0 + rr;
    gi[(rowc * 3 + 0) * 64 + lane] = ar[rr];
    gi[(rowc * 3 + 1) * 64 + lane] = az[rr];
    gi[(rowc * 3 + 2) * 64 + lane] = an[rr];
  }
}

// ---------------------------------------------------------------------------
// GRU scan over one chunk (gh only; whh streamed; h broadcast via LDS rows)
// ---------------------------------------------------------------------------
__global__ __launch_bounds__(256) void k_gru_scan4(
    const float* __restrict__ gi, const float4* __restrict__ whhP,
    const float* __restrict__ bhh, float* __restrict__ hstate,
    int t0, int nt) {
  __shared__ float h_s[16][64];
  int b = blockIdx.x >> 4;
  int i0 = (blockIdx.x & 15) * 16;
  int tid = threadIdx.x, w = tid >> 6, lane = tid & 63;
  float bh_r = bhh[lane], bh_z = bhh[64 + lane], bh_n = bhh[128 + lane];
  float h_reg[4];
#pragma unroll
  for (int rr = 0; rr < 4; ++rr) {
    float hv = (t0 == 0) ? 0.f
                         : hstate[((long)b * Nn + i0 + w * 4 + rr) * Hh + lane];
    h_reg[rr] = hv;
    h_s[w * 4 + rr][lane] = hv;
  }
  for (int tl = 0; tl < nt; ++tl) {
    long rbase = ((long)tl * Bsz + b) * Nn + i0 + w * 4;
    float gr[4], gz[4], gn[4], hr[4], hz[4], hn[4];
#pragma unroll
    for (int rr = 0; rr < 4; ++rr) {
      gr[rr] = gi[((rbase + rr) * 3 + 0) * 64 + lane];
      gz[rr] = gi[((rbase + rr) * 3 + 1) * 64 + lane];
      gn[rr] = gi[((rbase + rr) * 3 + 2) * 64 + lane];
      hr[rr] = bh_r; hz[rr] = bh_z; hn[rr] = bh_n;
    }
#pragma unroll 4
    for (int kb = 0; kb < 16; ++kb) {
      int k0 = kb * 4;
      float4 wh0 = whhP[(k0 + 0) * 64 + lane];
      float4 wh1 = whhP[(k0 + 1) * 64 + lane];
      float4 wh2 = whhP[(k0 + 2) * 64 + lane];
      float4 wh3 = whhP[(k0 + 3) * 64 + lane];
#pragma unroll
      for (int rr = 0; rr < 4; ++rr) {
        const float4 h4 = *(const float4*)&h_s[w * 4 + rr][k0];
        hr[rr] += h4.x * wh0.x + h4.y * wh1.x + h4.z * wh2.x + h4.w * wh3.x;
        hz[rr] += h4.x * wh0.y + h4.y * wh1.y + h4.z * wh2.y + h4.w * wh3.y;
        hn[rr] += h4.x * wh0.z + h4.y * wh1.z + h4.z * wh2.z + h4.w * wh3.z;
      }
    }
#pragma unroll
    for (int rr = 0; rr < 4; ++rr) {
      float rg = 1.f / (1.f + expf(-(gr[rr] + hr[rr])));
      float zg = 1.f / (1.f + expf(-(gz[rr] + hz[rr])));
      float ng = tanhf(gn[rr] + rg * hn[rr]);
      float hv = (1.f - zg) * ng + zg * h_reg[rr];
      h_reg[rr] = hv;
      h_s[w * 4 + rr][lane] = hv;
    }
  }
#pragma unroll
  for (int rr = 0; rr < 4; ++rr)
    hstate[((long)b * Nn + i0 + w * 4 + rr) * Hh + lane] = h_reg[rr];
}

// ---------------------------------------------------------------------------
// D0: decoder normalized adjacencies: A1d[i][j], A2d[i][j] (t = Tt-1)
// ---------------------------------------------------------------------------
__global__ __launch_bounds__(256) void k_norm_dec(
    const float* __restrict__ hw, const float2* __restrict__ pk,
    const float* __restrict__ d23, const float* __restrict__ e23,
    float* __restrict__ A1d, float* __restrict__ A2d) {
  int b = blockIdx.x >> 8;
  int i = blockIdx.x & 255;
  int j = threadIdx.x;
  float spd = hw[(b * Tt + (Tt - 1)) * Fw + 2];
  float rad = hw[(b * Tt + (Tt - 1)) * Fw + 1] * DEG2RAD;
  float cr = cosf(rad), sr = sinf(rad);
  const float* drow = d23 + b * Nn;
  const float* erow = e23 + b * Nn;
  float2 pv = pk[i * Nn + j];
  float val = spd * (pv.x * cr + pv.y * sr);
  float dlt = (j == i) ? 1.f : 0.f;
  float wout = fmaxf(val, 0.f);
  float win  = (j == i) ? wout : fmaxf(-val, 0.f);
  A1d[((long)b * Nn + i) * Nn + j] = drow[i] * (wout + dlt) * drow[j];
  A2d[((long)b * Nn + i) * Nn + j] = erow[i] * (win + dlt) * erow[j];
}

// ---------------------------------------------------------------------------
// dec0: x0 = mlp(h) for all B*N rows
// ---------------------------------------------------------------------------
__global__ __launch_bounds__(256) void k_dec0(
    const float* __restrict__ hstate,
    const float* __restrict__ wm1T, const float* __restrict__ bm1,
    const float* __restrict__ wm2T, const float* __restrict__ bm2,
    float* __restrict__ xnext) {
  const int RPB = 16;
  __shared__ float h_lds[RPB][Hh];
  __shared__ float u_lds[RPB][M1];
  int r0 = blockIdx.x * RPB;
  int tid = threadIdx.x;
#pragma unroll
  for (int c = 0; c < (RPB * Hh) / 256; ++c) {
    int idx = tid + c * 256;
    h_lds[idx >> 6][idx & 63] = hstate[(long)r0 * Hh + idx];
  }
  __syncthreads();
#pragma unroll
  for (int rep = 0; rep < 2; ++rep) {
    int idx = tid + rep * 256;
    int row = idx >> 5, m = idx & 31;
    float um = bm1[m];
    for (int k = 0; k < Hh; ++k) um += wm1T[k * M1 + m] * h_lds[row][k];
    u_lds[row][m] = fmaxf(um, 0.f);
  }
  __syncthreads();
  if (tid < RPB * Fp) {
    int row = tid / Fp, f = tid % Fp;
    float pf = bm2[f];
#pragma unroll
    for (int m = 0; m < M1; ++m) pf += wm2T[m * Fp + f] * u_lds[row][m];
    xnext[(r0 + row) * Fp + f] = pf;
  }
}

// ---------------------------------------------------------------------------
// Ddec A: gconv1 for decoder (A1d rows, shuffle reduce) -> h1d
// ---------------------------------------------------------------------------
__global__ __launch_bounds__(256) void k_dstep_A(
    const float* __restrict__ xb, const float* __restrict__ A1d,
    const float* __restrict__ wgc1, const float* __restrict__ bgc1,
    float* __restrict__ h1d) {
  __shared__ float x_lds[Nn * Fp];
  int b = blockIdx.x >> 4;
  int i0 = (blockIdx.x & 15) * 16;
  int tid = threadIdx.x, w = tid >> 6, lane = tid & 63;
  const float* xsrc = xb + (long)b * Nn * Fp;
#pragma unroll
  for (int c = 0; c < 6; ++c) x_lds[tid + 256 * c] = xsrc[tid + 256 * c];
  __syncthreads();
#pragma unroll
  for (int rr = 0; rr < 4; ++rr) {
    int i = i0 + w * 4 + rr;
    const float* arow = A1d + ((long)b * Nn + i) * Nn;
    float acc[Fp] = {0.f, 0.f, 0.f, 0.f, 0.f, 0.f};
#pragma unroll
    for (int c = 0; c < 4; ++c) {
      int j = lane + 64 * c;
      float wt = arow[j];
#pragma unroll
      for (int f = 0; f < Fp; ++f) acc[f] += wt * x_lds[j * Fp + f];
    }
#pragma unroll
    for (int f = 0; f < Fp; ++f) {
#pragma unroll
      for (int off = 32; off; off >>= 1) acc[f] += __shfl_xor(acc[f], off);
    }
    float hv = bgc1[lane];
#pragma unroll
    for (int f = 0; f < Fp; ++f) hv += wgc1[lane * Fp + f] * acc[f];
    h1d[((long)b * Nn + i) * Hh + lane] = fmaxf(hv, 0.f);
  }
}

// ---------------------------------------------------------------------------
// Ddec B: gconv2 + W2 + GRU (streamed weights) + MLP -> out, xnext
// ---------------------------------------------------------------------------
__global__ __launch_bounds__(256) void k_dstep_B(
    const float* __restrict__ A2d, const float* __restrict__ h1d,
    const float* __restrict__ wgc2T, const float* __restrict__ bgc2,
    const float4* __restrict__ wihP, const float4* __restrict__ whhP,
    const float* __restrict__ bih, const float* __restrict__ bhh,
    float* __restrict__ hstate,
    const float* __restrict__ wm1T, const float* __restrict__ bm1,
    const float* __restrict__ wm2T, const float* __restrict__ bm2,
    float* __restrict__ outp, float* __restrict__ xnext, int p) {
  __shared__ __align__(16) float wvT[Nn * 20];
  __shared__ float red[4][16][Hh];
  __shared__ float y2[16][Hh];
  __shared__ float sf_s[16][Hh];
  __shared__ float h_s[16][Hh];
  __shared__ float hn_lds[16][Hh];
  __shared__ float u_lds[16][M1];
  int b = blockIdx.x >> 4;
  int i0 = (blockIdx.x & 15) * 16;
  int tid = threadIdx.x, w = tid >> 6, lane = tid & 63;

#pragma unroll
  for (int r = 0; r < 16; ++r)
    wvT[tid * 20 + r] = A2d[((long)b * Nn + i0 + r) * Nn + tid];
  float hp_reg[4];
#pragma unroll
  for (int rr = 0; rr < 4; ++rr) {
    hp_reg[rr] = hstate[((long)b * Nn + i0 + w * 4 + rr) * Hh + lane];
    h_s[w * 4 + rr][lane] = hp_reg[rr];
  }
  __syncthreads();

  float acc[16];
#pragma unroll
  for (int r = 0; r < 16; ++r) acc[r] = 0.f;
  const float* h1b = h1d + (long)b * Nn * Hh;
#pragma unroll 4
  for (int jj = 0; jj < 64; ++jj) {
    int j = w * 64 + jj;
    float hv = h1b[j * Hh + lane];
    const float4* wp = (const float4*)(wvT + j * 20);
    float4 w0 = wp[0], w1 = wp[1], w2 = wp[2], w3 = wp[3];
    acc[0] += w0.x * hv; acc[1] += w0.y * hv; acc[2] += w0.z * hv; acc[3] += w0.w * hv;
    acc[4] += w1.x * hv; acc[5] += w1.y * hv; acc[6] += w1.z * hv; acc[7] += w1.w * hv;
    acc[8] += w2.x * hv; acc[9] += w2.y * hv; acc[10] += w2.z * hv; acc[11] += w2.w * hv;
    acc[12] += w3.x * hv; acc[13] += w3.y * hv; acc[14] += w3.z * hv; acc[15] += w3.w * hv;
  }
#pragma unroll
  for (int r = 0; r < 16; ++r) red[w][r][lane] = acc[r];
  __syncthreads();
#pragma unroll
  for (int rr = 0; rr < 4; ++rr) {
    int r = w * 4 + rr;
    y2[r][lane] = red[0][r][lane] + red[1][r][lane] + red[2][r][lane] + red[3][r][lane];
  }
  {
    float a0 = bgc2[lane], a1 = a0, a2 = a0, a3 = a0;
    for (int k = 0; k < Hh; ++k) {
      float wk = wgc2T[k * Hh + lane];
      a0 += wk * y2[w * 4 + 0][k];
      a1 += wk * y2[w * 4 + 1][k];
      a2 += wk * y2[w * 4 + 2][k];
      a3 += wk * y2[w * 4 + 3][k];
    }
    sf_s[w * 4 + 0][lane] = fmaxf(a0, 0.f);
    sf_s[w * 4 + 1][lane] = fmaxf(a1, 0.f);
    sf_s[w * 4 + 2][lane] = fmaxf(a2, 0.f);
    sf_s[w * 4 + 3][lane] = fmaxf(a3, 0.f);
  }

  float hn_reg[4];
  {
    float bi_r = bih[lane], bi_z = bih[64 + lane], bi_n = bih[128 + lane];
    float bh_r = bhh[lane], bh_z = bhh[64 + lane], bh_n = bhh[128 + lane];
    float gir[4], giz[4], gin[4], ghr[4], ghz[4], ghn[4];
#pragma unroll
    for (int rr = 0; rr < 4; ++rr) {
      gir[rr] = bi_r; giz[rr] = bi_z; gin[rr] = bi_n;
      ghr[rr] = bh_r; ghz[rr] = bh_z; ghn[rr] = bh_n;
    }
#pragma unroll 4
    for (int kb = 0; kb < 16; ++kb) {
      int k0 = kb * 4;
      float4 wi[4], wh[4];
#pragma unroll
      for (int q = 0; q < 4; ++q) {
        wi[q] = wihP[(k0 + q) * 64 + lane];
        wh[q] = whhP[(k0 + q) * 64 + lane];
      }
#pragma unroll
      for (int rr = 0; rr < 4; ++rr) {
        const float4 s4 = *(const float4*)&sf_s[w * 4 + rr][k0];
        const float4 h4 = *(const float4*)&h_s[w * 4 + rr][k0];
        gir[rr] += s4.x * wi[0].x + s4.y * wi[1].x + s4.z * wi[2].x + s4.w * wi[3].x;
        giz[rr] += s4.x * wi[0].y + s4.y * wi[1].y + s4.z * wi[2].y + s4.w * wi[3].y;
        gin[rr] += s4.x * wi[0].z + s4.y * wi[1].z + s4.z * wi[2].z + s4.w * wi[3].z;
        ghr[rr] += h4.x * wh[0].x + h4.y * wh[1].x + h4.z * wh[2].x + h4.w * wh[3].x;
        ghz[rr] += h4.x * wh[0].y + h4.y * wh[1].y + h4.z * wh[2].y + h4.w * wh[3].y;
        ghn[rr] += h4.x * wh[0].z + h4.y * wh[1].z + h4.z * wh[2].z + h4.w * wh[3].z;
      }
    }
#pragma unroll
    for (int rr = 0; rr < 4; ++rr) {
      float rg = 1.f / (1.f + expf(-(gir[rr] + ghr[rr])));
      float zg = 1.f / (1.f + expf(-(giz[rr] + ghz[rr])));
      float ng = tanhf(gin[rr] + rg * ghn[rr]);
      hn_reg[rr] = (1.f - zg) * ng + zg * hp_reg[rr];
      hstate[((long)b * Nn + i0 + w * 4 + rr) * Hh + lane] = hn_reg[rr];
      hn_lds[w * 4 + rr][lane] = hn_reg[rr];
    }
  }
  __syncthreads();
#pragma unroll
  for (int rep = 0; rep < 2; ++rep) {
    int idx = tid + rep * 256;
    int row = idx >> 5, m = idx & 31;
    float um = bm1[m];
    for (int k = 0; k < Hh; ++k) um += wm1T[k * M1 + m] * hn_lds[row][k];
    u_lds[row][m] = fmaxf(um, 0.f);
  }
  __syncthreads();
  if (tid < 16 * Fp) {
    int row = tid / Fp, f = tid % Fp;
    float pf = bm2[f];
#pragma unroll
    for (int m = 0; m < M1; ++m) pf += wm2T[m * Fp + f] * u_lds[row][m];
    int i = i0 + row;
    outp[(((long)b * PredL + p) * Nn + i) * Fp + f] = pf;
    xnext[((long)b * Nn + i) * Fp + f] = pf;
  }
}

// ---------------------------------------------------------------------------
extern "C" void kernel_launch(void* const* d_in, const int* in_sizes, int n_in,
                              void* d_out, int out_size, void* d_ws, size_t ws_size,
                              hipStream_t stream) {
  const float* hp     = (const float*)d_in[0];
  const float* hw     = (const float*)d_in[1];
  const float* adj    = (const float*)d_in[2];
  const float* coords = (const float*)d_in[3];
  const float* wgc1   = (const float*)d_in[4];
  const float* bgc1   = (const float*)d_in[5];
  const float* wgc2   = (const float*)d_in[6];
  const float* bgc2   = (const float*)d_in[7];
  const float* wih    = (const float*)d_in[8];
  const float* whh    = (const float*)d_in[9];
  const float* bih    = (const float*)d_in[10];
  const float* bhh    = (const float*)d_in[11];
  const float* wm1    = (const float*)d_in[12];
  const float* bm1    = (const float*)d_in[13];
  const float* wm2    = (const float*)d_in[14];
  const float* bm2    = (const float*)d_in[15];
  float* out = (float*)d_out;

  float* w = (float*)d_ws;
  float2* pk    = (float2*)w; w += Nn * Nn * 2;
  float* d23    = w; w += Bsz * Nn;
  float* e23    = w; w += Bsz * Nn;
  float* hstate = w; w += Bsz * Nn * Hh;
  float* sf_all = w; w += (long)Tt * Bsz * Nn * Hh;
  float* gi_ch  = w; w += (long)TCHUNK * Bsz * Nn * 3 * 64;
  float* h1d    = w; w += Bsz * Nn * Hh;
  float* xb0    = w; w += Bsz * Nn * Fp;
  float* xb1    = w; w += Bsz * Nn * Fp;
  float* A1d    = w; w += Bsz * Nn * Nn;
  float* A2d    = w; w += Bsz * Nn * Nn;
  float* wgc2T  = w; w += Hh * Hh;
  float* wm1T   = w; w += Hh * M1;
  float* wm2T   = w; w += M1 * Fp;
  float4* wihP  = (float4*)w; w += Hh * 64 * 4;
  float4* whhP  = (float4*)w; w += Hh * 64 * 4;

  k_prep<<<Nn + 1, 256, 0, stream>>>(coords, adj, wgc2, wih, whh, wm1, wm2,
                                     pk, wgc2T, wm1T, wm2T, wihP, whhP);
  k_enc<<<Tt * Bsz, 256, 0, stream>>>(pk, hp, hw, wgc1, bgc1, wgc2T, bgc2,
                                      sf_all, d23, e23);
  for (int s = 0; s < Tt / TCHUNK; ++s) {
    int t0 = s * TCHUNK;
    k_gi<<<(TCHUNK * Bsz * Nn) / 64, 256, 0, stream>>>(sf_all, wihP, bih,
                                                       gi_ch, t0);
    k_gru_scan4<<<Bsz * 16, 256, 0, stream>>>(gi_ch, whhP, bhh, hstate,
                                              t0, TCHUNK);
  }
  k_norm_dec<<<Bsz * Nn, 256, 0, stream>>>(hw, pk, d23, e23, A1d, A2d);
  k_dec0<<<Bsz * Nn / 16, 256, 0, stream>>>(hstate, wm1T, bm1, wm2T, bm2, xb0);

  for (int p = 0; p < PredL; ++p) {
    float* xin  = (p & 1) ? xb1 : xb0;
    float* xout = (p & 1) ? xb0 : xb1;
    k_dstep_A<<<Bsz * 16, 256, 0, stream>>>(xin, A1d, wgc1, bgc1, h1d);
    k_dstep_B<<<Bsz * 16, 256, 0, stream>>>(
        A2d, h1d, wgc2T, bgc2, wihP, whhP, bih, bhh, hstate,
        wm1T, bm1, wm2T, bm2, out, xout, p);
  }
}